// Round 5
// baseline (434.169 us; speedup 1.0000x reference)
//
#include <hip/hip_runtime.h>
#include <hip/hip_bf16.h>
#include <cstddef>

// ---------------- problem constants ----------------
constexpr int Ll   = 13294;
constexpr int NROW = 4 * Ll;     // 53176
constexpr int MP   = 53248;      // rows padded to multiple of 128
constexpr int CRp  = MP / 2;     // 26624 (FFN chunk rows)

typedef __bf16       bf8v __attribute__((ext_vector_type(8)));
typedef float        f4v  __attribute__((ext_vector_type(4)));
typedef unsigned int u4v  __attribute__((ext_vector_type(4)));

// =====================================================================
// bf16 MFMA GEMM (128x128 tile, BK=32, 4 waves 2x2, global_load_lds 16B)
// Swapped-operand MFMA: acc[nr][mr] = mfma(b,a) -> per-thread 4 CONSECUTIVE
// output cols per acc reg group: row = m0+wm*64+mr*16+fr, col = n0+wn*64+nr*16+fq*4+j
// A: [M][K] bf16 row-major. Bt: [N][K] bf16 (W^T). bias2: cols >= 256 (cat gemm).
// =====================================================================
template<bool RELU, bool OUTF, bool OUTB>
__global__ __launch_bounds__(256)
void gemm_mfma(const __hip_bfloat16* __restrict__ A, const __hip_bfloat16* __restrict__ Bt,
               const float* __restrict__ bias, const float* __restrict__ bias2,
               float* __restrict__ Cf, __hip_bfloat16* __restrict__ Cb,
               int M, int N, int K)
{
    __shared__ __hip_bfloat16 As[128 * 32];
    __shared__ __hip_bfloat16 Bs[128 * 32];
    const int tid  = threadIdx.x;
    const int wid  = tid >> 6;
    const int lane = tid & 63;
    const int m0 = blockIdx.y * 128;
    const int n0 = blockIdx.x * 128;
    const int wm = wid >> 1, wn = wid & 1;
    const int fr = lane & 15, fq = lane >> 4;
    const int sr = lane >> 2;
    const int sc = (lane & 3) * 8;

    f4v acc[4][4] = {};   // [nr][mr]

    for (int k0 = 0; k0 < K; k0 += 32) {
        #pragma unroll
        for (int i = 0; i < 2; ++i) {
            const int s = wid * 2 + i;
            const __hip_bfloat16* sa = A  + (size_t)(m0 + s * 16 + sr) * K + k0 + sc;
            const __hip_bfloat16* sb = Bt + (size_t)(n0 + s * 16 + sr) * K + k0 + sc;
            __builtin_amdgcn_global_load_lds(
                (const __attribute__((address_space(1))) void*)sa,
                (__attribute__((address_space(3))) void*)&As[s * 512], 16, 0, 0);
            __builtin_amdgcn_global_load_lds(
                (const __attribute__((address_space(1))) void*)sb,
                (__attribute__((address_space(3))) void*)&Bs[s * 512], 16, 0, 0);
        }
        __syncthreads();

        bf8v a[4], b[4];
        #pragma unroll
        for (int r = 0; r < 4; ++r) {
            a[r] = __builtin_bit_cast(bf8v, *(const u4v*)&As[(wm * 64 + r * 16 + fr) * 32 + fq * 8]);
            b[r] = __builtin_bit_cast(bf8v, *(const u4v*)&Bs[(wn * 64 + r * 16 + fr) * 32 + fq * 8]);
        }
        #pragma unroll
        for (int nr = 0; nr < 4; ++nr)
            #pragma unroll
            for (int mr = 0; mr < 4; ++mr)
                acc[nr][mr] = __builtin_amdgcn_mfma_f32_16x16x32_bf16(b[nr], a[mr], acc[nr][mr], 0, 0, 0);
        __syncthreads();
    }

    #pragma unroll
    for (int nr = 0; nr < 4; ++nr) {
        const int colbase = n0 + wn * 64 + nr * 16 + fq * 4;
        const float* bp = (bias2 != nullptr && colbase >= 256) ? (bias2 - 256) : bias;
        const float4 b4 = *(const float4*)&bp[colbase];
        #pragma unroll
        for (int mr = 0; mr < 4; ++mr) {
            const int row = m0 + wm * 64 + mr * 16 + fr;
            f4v v = acc[nr][mr];
            v[0] += b4.x; v[1] += b4.y; v[2] += b4.z; v[3] += b4.w;
            if (RELU) {
                v[0] = fmaxf(v[0], 0.f); v[1] = fmaxf(v[1], 0.f);
                v[2] = fmaxf(v[2], 0.f); v[3] = fmaxf(v[3], 0.f);
            }
            if (OUTF)
                *(float4*)&Cf[(size_t)row * N + colbase] = make_float4(v[0], v[1], v[2], v[3]);
            if (OUTB) {
                union { ushort4 u; __hip_bfloat16 h[4]; } pk;
                pk.h[0] = __float2bfloat16(v[0]); pk.h[1] = __float2bfloat16(v[1]);
                pk.h[2] = __float2bfloat16(v[2]); pk.h[3] = __float2bfloat16(v[3]);
                *(ushort4*)&Cb[(size_t)row * N + colbase] = pk.u;
            }
        }
    }
}

// =====================================================================
// bf16 MFMA GEMM (128x256 tile, N fixed 256) + residual + LayerNorm epilogue.
// x = acc + bias + res(row<Mres); LN over the block's full 256-col rows.
// Writes outF (f32, rows<MstoreF) and optionally outB (bf16, all rows).
// =====================================================================
template<bool STOREB>
__global__ __launch_bounds__(256)
void gemm_ln(const __hip_bfloat16* __restrict__ A, const __hip_bfloat16* __restrict__ Bt,
             const float* __restrict__ bias,
             const float* __restrict__ res, int Mres,
             const float* __restrict__ g, const float* __restrict__ be,
             float* __restrict__ outF, int MstoreF,
             __hip_bfloat16* __restrict__ outB,
             int M, int K)
{
    __shared__ __hip_bfloat16 As[128 * 32];
    __shared__ __hip_bfloat16 Bs[256 * 32];
    __shared__ float red[2][128][2];
    const int tid  = threadIdx.x;
    const int wid  = tid >> 6;
    const int lane = tid & 63;
    const int m0 = blockIdx.y * 128;
    const int wm = wid >> 1, wn = wid & 1;     // wave tile 64 rows x 128 cols
    const int fr = lane & 15, fq = lane >> 4;
    const int sr = lane >> 2;
    const int sc = (lane & 3) * 8;

    f4v acc[8][4] = {};   // [nr][mr]

    for (int k0 = 0; k0 < K; k0 += 32) {
        #pragma unroll
        for (int i = 0; i < 2; ++i) {
            const int s = wid * 2 + i;
            const __hip_bfloat16* sa = A + (size_t)(m0 + s * 16 + sr) * K + k0 + sc;
            __builtin_amdgcn_global_load_lds(
                (const __attribute__((address_space(1))) void*)sa,
                (__attribute__((address_space(3))) void*)&As[s * 512], 16, 0, 0);
        }
        #pragma unroll
        for (int i = 0; i < 4; ++i) {
            const int s = wid * 4 + i;
            const __hip_bfloat16* sb = Bt + (size_t)(s * 16 + sr) * K + k0 + sc;
            __builtin_amdgcn_global_load_lds(
                (const __attribute__((address_space(1))) void*)sb,
                (__attribute__((address_space(3))) void*)&Bs[s * 512], 16, 0, 0);
        }
        __syncthreads();

        bf8v a[4], b[8];
        #pragma unroll
        for (int r = 0; r < 4; ++r)
            a[r] = __builtin_bit_cast(bf8v, *(const u4v*)&As[(wm * 64 + r * 16 + fr) * 32 + fq * 8]);
        #pragma unroll
        for (int r = 0; r < 8; ++r)
            b[r] = __builtin_bit_cast(bf8v, *(const u4v*)&Bs[(wn * 128 + r * 16 + fr) * 32 + fq * 8]);
        #pragma unroll
        for (int nr = 0; nr < 8; ++nr)
            #pragma unroll
            for (int mr = 0; mr < 4; ++mr)
                acc[nr][mr] = __builtin_amdgcn_mfma_f32_16x16x32_bf16(b[nr], a[mr], acc[nr][mr], 0, 0, 0);
        __syncthreads();
    }

    // ---- epilogue: x = acc + bias + res; per-row partial sums
    float s4[4] = {}, q4[4] = {};
    #pragma unroll
    for (int nr = 0; nr < 8; ++nr) {
        const int colbase = wn * 128 + nr * 16 + fq * 4;
        const float4 b4 = *(const float4*)&bias[colbase];
        #pragma unroll
        for (int mr = 0; mr < 4; ++mr) {
            const int row = m0 + wm * 64 + mr * 16 + fr;
            f4v x = acc[nr][mr];
            x[0] += b4.x; x[1] += b4.y; x[2] += b4.z; x[3] += b4.w;
            if (row < Mres) {
                const float4 r4 = *(const float4*)&res[(size_t)row * 256 + colbase];
                x[0] += r4.x; x[1] += r4.y; x[2] += r4.z; x[3] += r4.w;
            }
            acc[nr][mr] = x;
            s4[mr] += x[0] + x[1] + x[2] + x[3];
            q4[mr] += x[0]*x[0] + x[1]*x[1] + x[2]*x[2] + x[3]*x[3];
        }
    }
    // reduce over fq (lane bits 4,5): lanes with same fr share rows
    #pragma unroll
    for (int mr = 0; mr < 4; ++mr) {
        s4[mr] += __shfl_xor(s4[mr], 16, 64);
        q4[mr] += __shfl_xor(q4[mr], 16, 64);
        s4[mr] += __shfl_xor(s4[mr], 32, 64);
        q4[mr] += __shfl_xor(q4[mr], 32, 64);
    }
    if (fq == 0) {
        #pragma unroll
        for (int mr = 0; mr < 4; ++mr) {
            red[wn][wm * 64 + mr * 16 + fr][0] = s4[mr];
            red[wn][wm * 64 + mr * 16 + fr][1] = q4[mr];
        }
    }
    __syncthreads();
    float mean[4], rinv[4];
    #pragma unroll
    for (int mr = 0; mr < 4; ++mr) {
        const int r = wm * 64 + mr * 16 + fr;
        const float ss = red[0][r][0] + red[1][r][0];
        const float qq = red[0][r][1] + red[1][r][1];
        mean[mr] = ss * (1.f / 256.f);
        const float var = qq * (1.f / 256.f) - mean[mr] * mean[mr];
        rinv[mr] = rsqrtf(var + 1e-5f);
    }
    #pragma unroll
    for (int nr = 0; nr < 8; ++nr) {
        const int colbase = wn * 128 + nr * 16 + fq * 4;
        const float4 g4 = *(const float4*)&g[colbase];
        const float4 e4 = *(const float4*)&be[colbase];
        #pragma unroll
        for (int mr = 0; mr < 4; ++mr) {
            const int row = m0 + wm * 64 + mr * 16 + fr;
            const f4v x = acc[nr][mr];
            float y0 = (x[0] - mean[mr]) * rinv[mr] * g4.x + e4.x;
            float y1 = (x[1] - mean[mr]) * rinv[mr] * g4.y + e4.y;
            float y2 = (x[2] - mean[mr]) * rinv[mr] * g4.z + e4.z;
            float y3 = (x[3] - mean[mr]) * rinv[mr] * g4.w + e4.w;
            if (row < MstoreF)
                *(float4*)&outF[(size_t)row * 256 + colbase] = make_float4(y0, y1, y2, y3);
            if (STOREB) {
                union { ushort4 u; __hip_bfloat16 h[4]; } pk;
                pk.h[0] = __float2bfloat16(y0); pk.h[1] = __float2bfloat16(y1);
                pk.h[2] = __float2bfloat16(y2); pk.h[3] = __float2bfloat16(y3);
                *(ushort4*)&outB[(size_t)row * 256 + colbase] = pk.u;
            }
        }
    }
}

// =====================================================================
// all weight prep in one launch: transpose + bf16 convert
// =====================================================================
__global__ __launch_bounds__(256)
void prep_weights(const float* __restrict__ vW, const float* __restrict__ offW,
                  const float* __restrict__ awW, const float* __restrict__ outW,
                  const float* __restrict__ w1, const float* __restrict__ w2,
                  __hip_bfloat16* __restrict__ vWt, __hip_bfloat16* __restrict__ catWt,
                  __hip_bfloat16* __restrict__ outWt, __hip_bfloat16* __restrict__ w1t,
                  __hip_bfloat16* __restrict__ w2t)
{
    int i = blockIdx.x * 256 + threadIdx.x;   // 753664 total = 2944*256
    if (i < 65536) { const int n = i >> 8, k = i & 255;
        vWt[i] = __float2bfloat16(vW[(size_t)k * 256 + n]); return; }
    i -= 65536;
    if (i < 98304) { const int n = i >> 8, k = i & 255;
        catWt[i] = __float2bfloat16(n < 256 ? offW[(size_t)k * 256 + n]
                                            : awW[(size_t)k * 128 + n - 256]); return; }
    i -= 98304;
    if (i < 65536) { const int n = i >> 8, k = i & 255;
        outWt[i] = __float2bfloat16(outW[(size_t)k * 256 + n]); return; }
    i -= 65536;
    if (i < 262144) { const int n = i >> 8, k = i & 255;
        w1t[i] = __float2bfloat16(w1[(size_t)k * 1024 + n]); return; }
    i -= 262144;
    { const int n = i >> 10, k = i & 1023;
        w2t[i] = __float2bfloat16(w2[(size_t)k * 256 + n]); }
}

// ---------------- query / query+pos -> bf16 (padded rows -> 0), one pass ----
__global__ __launch_bounds__(256)
void cvt_both(const float* __restrict__ q, const float* __restrict__ qp,
              __hip_bfloat16* __restrict__ qb, __hip_bfloat16* __restrict__ qpb)
{
    const int i   = blockIdx.x * 256 + threadIdx.x;  // 8-elem chunk id
    const int row = i >> 5;
    union { u4v u; __hip_bfloat16 h[8]; } p1, p2;
    if (row >= NROW) {
        u4v z = {0u, 0u, 0u, 0u};
        p1.u = z; p2.u = z;
    } else {
        const size_t e = (size_t)i * 8;
        float4 x0 = *(const float4*)&q[e];
        float4 x1 = *(const float4*)&q[e + 4];
        float4 y0 = *(const float4*)&qp[e];
        float4 y1 = *(const float4*)&qp[e + 4];
        p1.h[0] = __float2bfloat16(x0.x); p1.h[1] = __float2bfloat16(x0.y);
        p1.h[2] = __float2bfloat16(x0.z); p1.h[3] = __float2bfloat16(x0.w);
        p1.h[4] = __float2bfloat16(x1.x); p1.h[5] = __float2bfloat16(x1.y);
        p1.h[6] = __float2bfloat16(x1.z); p1.h[7] = __float2bfloat16(x1.w);
        p2.h[0] = __float2bfloat16(x0.x + y0.x); p2.h[1] = __float2bfloat16(x0.y + y0.y);
        p2.h[2] = __float2bfloat16(x0.z + y0.z); p2.h[3] = __float2bfloat16(x0.w + y0.w);
        p2.h[4] = __float2bfloat16(x1.x + y1.x); p2.h[5] = __float2bfloat16(x1.y + y1.y);
        p2.h[6] = __float2bfloat16(x1.z + y1.z); p2.h[7] = __float2bfloat16(x1.w + y1.w);
    }
    *(u4v*)&qb[(size_t)i * 8]  = p1.u;
    *(u4v*)&qpb[(size_t)i * 8] = p2.u;
}

// =====================================================================
// MSDA sampling v3 (unchanged structure; reads fused cat buffer, stride 384)
// =====================================================================
__device__ __forceinline__ float blo(unsigned u) { return __builtin_bit_cast(float, u << 16); }
__device__ __forceinline__ float bhi(unsigned u) { return __builtin_bit_cast(float, u & 0xffff0000u); }

__global__ __launch_bounds__(256)
void msda_sample3(const __hip_bfloat16* __restrict__ v, const float* __restrict__ cat,
                  const float* __restrict__ refp, __hip_bfloat16* __restrict__ accO)
{
    __shared__ int   sIdx[1024][4];
    __shared__ float sW[1024][4];
    const int row0 = blockIdx.x * 8;
    const int tid  = threadIdx.x;

    #pragma unroll
    for (int it = 0; it < 4; ++it) {
        const int item = it * 256 + tid;          // (r<<7)|(h<<4)|p
        const int p = item & 15, h = (item >> 4) & 7, r = item >> 7;
        const int row = row0 + r;
        const int lvl = p >> 2;
        const float logit = cat[(size_t)row * 384 + 256 + h * 16 + p];
        float mx = logit;
        #pragma unroll
        for (int o = 1; o < 16; o <<= 1) mx = fmaxf(mx, __shfl_xor(mx, o, 64));
        const float e = __expf(logit - mx);
        float s = e;
        #pragma unroll
        for (int o = 1; o < 16; o <<= 1) s += __shfl_xor(s, o, 64);
        const float aw = e / s;

        const int Hs[4] = {100, 50, 25, 13};
        const int Ss[4] = {0, 10000, 12500, 13125};
        const int   Wl = Hs[lvl];
        const float Wf = (float)Wl;
        const float ox = cat[(size_t)row * 384 + h * 32 + p * 2 + 0];
        const float oy = cat[(size_t)row * 384 + h * 32 + p * 2 + 1];
        const float rx = refp[(size_t)row * 8 + lvl * 2 + 0];
        const float ry = refp[(size_t)row * 8 + lvl * 2 + 1];
        const float x = (rx + ox / Wf) * Wf - 0.5f;
        const float y = (ry + oy / Wf) * Wf - 0.5f;
        const float x0f = floorf(x), y0f = floorf(y);
        const float lx = x - x0f, ly = y - y0f;
        const int x0 = (int)x0f, y0 = (int)y0f;
        const int b = row / Ll;
        const int vbase = b * Ll + Ss[lvl];
        int ixr[4]; float wr[4];
        #pragma unroll
        for (int c = 0; c < 4; ++c) {
            const int cy = c >> 1, cx = c & 1;
            const int yi = y0 + cy, xi = x0 + cx;
            const bool ok = (yi >= 0) & (yi < Wl) & (xi >= 0) & (xi < Wl);
            const int yc = min(max(yi, 0), Wl - 1);
            const int xc = min(max(xi, 0), Wl - 1);
            const float wt = (cy ? ly : 1.f - ly) * (cx ? lx : 1.f - lx);
            ixr[c] = (vbase + yc * Wl + xc) * 512;
            wr[c]  = ok ? aw * wt : 0.f;
        }
        const int item2 = (item & ~15) | ((item & 15) ^ h);  // bank swizzle
        *(int4*)&sIdx[item2][0] = make_int4(ixr[0], ixr[1], ixr[2], ixr[3]);
        *(float4*)&sW[item2][0] = make_float4(wr[0], wr[1], wr[2], wr[3]);
    }
    __syncthreads();

    const int r   = tid >> 5;
    const int h   = (tid >> 2) & 7;
    const int oct = tid & 3;
    const int row = row0 + r;
    const char* vB = (const char*)v + (h * 32 + oct * 8) * 2;
    const int ibase = r * 128 + h * 16;
    float acc[8] = {};
    #pragma unroll
    for (int i = 0; i < 16; ++i) {
        const int idx = ibase + (i ^ h);
        const int4   ix = *(const int4*)&sIdx[idx][0];
        const float4 wv = *(const float4*)&sW[idx][0];
        u4v u0 = *(const u4v*)(vB + (unsigned)ix.x);
        u4v u1 = *(const u4v*)(vB + (unsigned)ix.y);
        u4v u2 = *(const u4v*)(vB + (unsigned)ix.z);
        u4v u3 = *(const u4v*)(vB + (unsigned)ix.w);
        #pragma unroll
        for (int q = 0; q < 4; ++q) {
            acc[2*q]   = fmaf(wv.x, blo(u0[q]), acc[2*q]);
            acc[2*q+1] = fmaf(wv.x, bhi(u0[q]), acc[2*q+1]);
            acc[2*q]   = fmaf(wv.y, blo(u1[q]), acc[2*q]);
            acc[2*q+1] = fmaf(wv.y, bhi(u1[q]), acc[2*q+1]);
            acc[2*q]   = fmaf(wv.z, blo(u2[q]), acc[2*q]);
            acc[2*q+1] = fmaf(wv.z, bhi(u2[q]), acc[2*q+1]);
            acc[2*q]   = fmaf(wv.w, blo(u3[q]), acc[2*q]);
            acc[2*q+1] = fmaf(wv.w, bhi(u3[q]), acc[2*q+1]);
        }
    }
    union { u4v u; __hip_bfloat16 hh[8]; } pk;
    #pragma unroll
    for (int q = 0; q < 8; ++q) pk.hh[q] = __float2bfloat16(acc[q]);
    *(u4v*)&accO[(size_t)row * 256 + h * 32 + oct * 8] = pk.u;
}

// =====================================================================
// launcher
// =====================================================================
extern "C" void kernel_launch(void* const* d_in, const int* in_sizes, int n_in,
                              void* d_out, int out_size, void* d_ws, size_t ws_size,
                              hipStream_t stream)
{
    (void)in_sizes; (void)n_in; (void)out_size; (void)ws_size;
    const float* query = (const float*)d_in[0];
    const float* qpos  = (const float*)d_in[1];
    const float* refp  = (const float*)d_in[2];
    const float* v_W   = (const float*)d_in[5];
    const float* v_b   = (const float*)d_in[6];
    const float* off_W = (const float*)d_in[7];
    const float* off_b = (const float*)d_in[8];
    const float* aw_W  = (const float*)d_in[9];
    const float* aw_b  = (const float*)d_in[10];
    const float* out_W = (const float*)d_in[11];
    const float* out_b = (const float*)d_in[12];
    const float* ln1g  = (const float*)d_in[13];
    const float* ln1b  = (const float*)d_in[14];
    const float* w1    = (const float*)d_in[15];
    const float* b1    = (const float*)d_in[16];
    const float* w2    = (const float*)d_in[17];
    const float* b2    = (const float*)d_in[18];
    const float* ln2g  = (const float*)d_in[19];
    const float* ln2b  = (const float*)d_in[20];
    float* out = (float*)d_out;

    char* ws = (char*)d_ws;
    // arena (peak 165,085,184 B — same as prior rounds):
    //   [0, 81.8M)        catf f32 [MP][384]      -> later xf f32 [MP][256]
    //   [81.8M, 109.1M)   qb bf16                 -> accb -> hbuf (spans both)
    //   [109.1M, 136.3M)  qpb bf16                -> hbuf tail
    //   [136.3M, 163.6M)  vbuf bf16               -> xb bf16
    //   [163.6M, 165.1M)  weights
    constexpr size_t CATF_B = (size_t)MP * 384 * 4;     //  81,788,928
    constexpr size_t HALF_B = (size_t)MP * 256 * 2;     //  27,262,976
    float*          catf = (float*)ws;
    __hip_bfloat16* qb   = (__hip_bfloat16*)(ws + CATF_B);
    __hip_bfloat16* qpb  = (__hip_bfloat16*)(ws + CATF_B + HALF_B);
    __hip_bfloat16* vbuf = (__hip_bfloat16*)(ws + CATF_B + 2 * HALF_B);
    __hip_bfloat16* accb = qb;
    float*          xf   = (float*)ws;
    __hip_bfloat16* xb   = vbuf;
    __hip_bfloat16* hbuf = qb;
    char* wsw = ws + CATF_B + 3 * HALF_B;
    __hip_bfloat16* vWt   = (__hip_bfloat16*)(wsw);
    __hip_bfloat16* catWt = (__hip_bfloat16*)(wsw + 131072);
    __hip_bfloat16* outWt = (__hip_bfloat16*)(wsw + 327680);
    __hip_bfloat16* w1t   = (__hip_bfloat16*)(wsw + 458752);
    __hip_bfloat16* w2t   = (__hip_bfloat16*)(wsw + 983040);

    dim3 blk(256);

    prep_weights<<<2944, blk, 0, stream>>>(v_W, off_W, aw_W, out_W, w1, w2,
                                           vWt, catWt, outWt, w1t, w2t);
    cvt_both<<<MP / 8, blk, 0, stream>>>(query, qpos, qb, qpb);

    // v = query @ v_W + v_b  (bf16 out)
    gemm_mfma<false, false, true><<<dim3(2, MP / 128), blk, 0, stream>>>(
        qb, vWt, v_b, nullptr, nullptr, vbuf, MP, 256, 256);
    // cat = (q+pos) @ [off_W | aw_W] + [off_b | aw_b]  (f32 out, N=384)
    gemm_mfma<false, true, false><<<dim3(3, MP / 128), blk, 0, stream>>>(
        qpb, catWt, off_b, aw_b, catf, nullptr, MP, 384, 256);

    // deformable sampling
    msda_sample3<<<NROW / 8, blk, 0, stream>>>(vbuf, catf, refp, accb);

    // src2 = acc @ out_W + out_b ; x = LN1(query + src2)  (fused)
    gemm_ln<true><<<dim3(1, MP / 128), blk, 0, stream>>>(
        accb, outWt, out_b, query, NROW, ln1g, ln1b, xf, MP, xb, MP, 256);

    // FFN + LN2 in 2 row-chunks
    for (int c = 0; c < 2; ++c) {
        gemm_mfma<true, false, true><<<dim3(8, CRp / 128), blk, 0, stream>>>(
            xb + (size_t)c * CRp * 256, w1t, b1, nullptr, nullptr, hbuf, CRp, 1024, 256);
        const int mstore = (c == 0) ? CRp : (NROW - CRp);
        gemm_ln<false><<<dim3(1, CRp / 128), blk, 0, stream>>>(
            hbuf, w2t, b2, xf + (size_t)c * CRp * 256, CRp, ln2g, ln2b,
            out + (size_t)c * CRp * 256, mstore, nullptr, CRp, 1024);
    }
}

// Round 6
// 364.154 us; speedup vs baseline: 1.1923x; 1.1923x over previous
//
#include <hip/hip_runtime.h>
#include <hip/hip_bf16.h>
#include <cstddef>

// ---------------- problem constants ----------------
constexpr int Ll   = 13294;
constexpr int NROW = 4 * Ll;     // 53176
constexpr int MP   = 53248;      // rows padded to multiple of 128

typedef __bf16       bf8v __attribute__((ext_vector_type(8)));
typedef float        f4v  __attribute__((ext_vector_type(4)));
typedef unsigned int u4v  __attribute__((ext_vector_type(4)));

// =====================================================================
// bf16 MFMA GEMM (128x128 tile, BK=32, 4 waves 2x2, global_load_lds 16B)
// Swapped-operand MFMA: acc[nr][mr] = mfma(b,a) -> thread owns 4 CONSECUTIVE
// output cols: row = m0+wm*64+mr*16+fr, col = n0+wn*64+nr*16+fq*4+j
// A: [M][K] bf16 row-major. Bt: [N][K] bf16 (W^T). bias2: cols >= 256.
// =====================================================================
template<bool RELU, bool OUTF, bool OUTB>
__global__ __launch_bounds__(256)
void gemm_mfma(const __hip_bfloat16* __restrict__ A, const __hip_bfloat16* __restrict__ Bt,
               const float* __restrict__ bias, const float* __restrict__ bias2,
               float* __restrict__ Cf, __hip_bfloat16* __restrict__ Cb,
               int M, int N, int K)
{
    __shared__ __hip_bfloat16 As[128 * 32];
    __shared__ __hip_bfloat16 Bs[128 * 32];
    const int tid  = threadIdx.x;
    const int wid  = tid >> 6;
    const int lane = tid & 63;
    const int m0 = blockIdx.y * 128;
    const int n0 = blockIdx.x * 128;
    const int wm = wid >> 1, wn = wid & 1;
    const int fr = lane & 15, fq = lane >> 4;
    const int sr = lane >> 2;
    const int sc = (lane & 3) * 8;

    f4v acc[4][4] = {};   // [nr][mr]

    for (int k0 = 0; k0 < K; k0 += 32) {
        #pragma unroll
        for (int i = 0; i < 2; ++i) {
            const int s = wid * 2 + i;
            const __hip_bfloat16* sa = A  + (size_t)(m0 + s * 16 + sr) * K + k0 + sc;
            const __hip_bfloat16* sb = Bt + (size_t)(n0 + s * 16 + sr) * K + k0 + sc;
            __builtin_amdgcn_global_load_lds(
                (const __attribute__((address_space(1))) void*)sa,
                (__attribute__((address_space(3))) void*)&As[s * 512], 16, 0, 0);
            __builtin_amdgcn_global_load_lds(
                (const __attribute__((address_space(1))) void*)sb,
                (__attribute__((address_space(3))) void*)&Bs[s * 512], 16, 0, 0);
        }
        __syncthreads();

        bf8v a[4], b[4];
        #pragma unroll
        for (int r = 0; r < 4; ++r) {
            a[r] = __builtin_bit_cast(bf8v, *(const u4v*)&As[(wm * 64 + r * 16 + fr) * 32 + fq * 8]);
            b[r] = __builtin_bit_cast(bf8v, *(const u4v*)&Bs[(wn * 64 + r * 16 + fr) * 32 + fq * 8]);
        }
        #pragma unroll
        for (int nr = 0; nr < 4; ++nr)
            #pragma unroll
            for (int mr = 0; mr < 4; ++mr)
                acc[nr][mr] = __builtin_amdgcn_mfma_f32_16x16x32_bf16(b[nr], a[mr], acc[nr][mr], 0, 0, 0);
        __syncthreads();
    }

    #pragma unroll
    for (int nr = 0; nr < 4; ++nr) {
        const int colbase = n0 + wn * 64 + nr * 16 + fq * 4;
        const float* bp = (bias2 != nullptr && colbase >= 256) ? (bias2 - 256) : bias;
        const float4 b4 = *(const float4*)&bp[colbase];
        #pragma unroll
        for (int mr = 0; mr < 4; ++mr) {
            const int row = m0 + wm * 64 + mr * 16 + fr;
            f4v v = acc[nr][mr];
            v[0] += b4.x; v[1] += b4.y; v[2] += b4.z; v[3] += b4.w;
            if (RELU) {
                v[0] = fmaxf(v[0], 0.f); v[1] = fmaxf(v[1], 0.f);
                v[2] = fmaxf(v[2], 0.f); v[3] = fmaxf(v[3], 0.f);
            }
            if (OUTF)
                *(float4*)&Cf[(size_t)row * N + colbase] = make_float4(v[0], v[1], v[2], v[3]);
            if (OUTB) {
                union { ushort4 u; __hip_bfloat16 h[4]; } pk;
                pk.h[0] = __float2bfloat16(v[0]); pk.h[1] = __float2bfloat16(v[1]);
                pk.h[2] = __float2bfloat16(v[2]); pk.h[3] = __float2bfloat16(v[3]);
                *(ushort4*)&Cb[(size_t)row * N + colbase] = pk.u;
            }
        }
    }
}

// =====================================================================
// bf16 MFMA GEMM (64x256 tile, N fixed 256) + residual + LayerNorm epilogue.
// 4 waves 2x2, wave = 32 rows x 128 cols; acc[8][2].
// x = acc + bias + res; LN over 256 cols; write outF (f32, row<MstoreF)
// and/or outB (bf16, all rows). RESB: residual is bf16 (else f32, row<Mres).
// =====================================================================
template<bool STOREB, bool RESB>
__global__ __launch_bounds__(256)
void gemm_ln(const __hip_bfloat16* __restrict__ A, const __hip_bfloat16* __restrict__ Bt,
             const float* __restrict__ bias,
             const float* __restrict__ resF, const __hip_bfloat16* __restrict__ resB,
             int Mres,
             const float* __restrict__ g, const float* __restrict__ be,
             float* __restrict__ outF, int MstoreF,
             __hip_bfloat16* __restrict__ outB,
             int K)
{
    __shared__ __hip_bfloat16 As[64 * 32];
    __shared__ __hip_bfloat16 Bs[256 * 32];
    __shared__ float red[2][64][2];
    const int tid  = threadIdx.x;
    const int wid  = tid >> 6;
    const int lane = tid & 63;
    const int m0 = blockIdx.x * 64;
    const int wm = wid >> 1, wn = wid & 1;     // wave: 32 rows x 128 cols
    const int fr = lane & 15, fq = lane >> 4;
    const int sr = lane >> 2;
    const int sc = (lane & 3) * 8;

    f4v acc[8][2] = {};   // [nr][mr]

    for (int k0 = 0; k0 < K; k0 += 32) {
        {
            const __hip_bfloat16* sa = A + (size_t)(m0 + wid * 16 + sr) * K + k0 + sc;
            __builtin_amdgcn_global_load_lds(
                (const __attribute__((address_space(1))) void*)sa,
                (__attribute__((address_space(3))) void*)&As[wid * 512], 16, 0, 0);
        }
        #pragma unroll
        for (int i = 0; i < 4; ++i) {
            const int s = wid * 4 + i;
            const __hip_bfloat16* sb = Bt + (size_t)(s * 16 + sr) * K + k0 + sc;
            __builtin_amdgcn_global_load_lds(
                (const __attribute__((address_space(1))) void*)sb,
                (__attribute__((address_space(3))) void*)&Bs[s * 512], 16, 0, 0);
        }
        __syncthreads();

        bf8v a[2], b[8];
        #pragma unroll
        for (int r = 0; r < 2; ++r)
            a[r] = __builtin_bit_cast(bf8v, *(const u4v*)&As[(wm * 32 + r * 16 + fr) * 32 + fq * 8]);
        #pragma unroll
        for (int r = 0; r < 8; ++r)
            b[r] = __builtin_bit_cast(bf8v, *(const u4v*)&Bs[(wn * 128 + r * 16 + fr) * 32 + fq * 8]);
        #pragma unroll
        for (int nr = 0; nr < 8; ++nr)
            #pragma unroll
            for (int mr = 0; mr < 2; ++mr)
                acc[nr][mr] = __builtin_amdgcn_mfma_f32_16x16x32_bf16(b[nr], a[mr], acc[nr][mr], 0, 0, 0);
        __syncthreads();
    }

    // ---- epilogue: x = acc + bias + res; per-row partial sums
    float s2[2] = {}, q2[2] = {};
    #pragma unroll
    for (int nr = 0; nr < 8; ++nr) {
        const int colbase = wn * 128 + nr * 16 + fq * 4;
        const float4 b4 = *(const float4*)&bias[colbase];
        #pragma unroll
        for (int mr = 0; mr < 2; ++mr) {
            const int row = m0 + wm * 32 + mr * 16 + fr;
            f4v x = acc[nr][mr];
            x[0] += b4.x; x[1] += b4.y; x[2] += b4.z; x[3] += b4.w;
            if (RESB) {
                const ushort4 r4 = *(const ushort4*)&resB[(size_t)row * 256 + colbase];
                x[0] += __builtin_bit_cast(float, (unsigned)r4.x << 16);
                x[1] += __builtin_bit_cast(float, (unsigned)r4.y << 16);
                x[2] += __builtin_bit_cast(float, (unsigned)r4.z << 16);
                x[3] += __builtin_bit_cast(float, (unsigned)r4.w << 16);
            } else if (row < Mres) {
                const float4 r4 = *(const float4*)&resF[(size_t)row * 256 + colbase];
                x[0] += r4.x; x[1] += r4.y; x[2] += r4.z; x[3] += r4.w;
            }
            acc[nr][mr] = x;
            s2[mr] += x[0] + x[1] + x[2] + x[3];
            q2[mr] += x[0]*x[0] + x[1]*x[1] + x[2]*x[2] + x[3]*x[3];
        }
    }
    // reduce over fq (lane bits 4,5)
    #pragma unroll
    for (int mr = 0; mr < 2; ++mr) {
        s2[mr] += __shfl_xor(s2[mr], 16, 64);
        q2[mr] += __shfl_xor(q2[mr], 16, 64);
        s2[mr] += __shfl_xor(s2[mr], 32, 64);
        q2[mr] += __shfl_xor(q2[mr], 32, 64);
    }
    if (fq == 0) {
        #pragma unroll
        for (int mr = 0; mr < 2; ++mr) {
            red[wn][wm * 32 + mr * 16 + fr][0] = s2[mr];
            red[wn][wm * 32 + mr * 16 + fr][1] = q2[mr];
        }
    }
    __syncthreads();
    float mean[2], rinv[2];
    #pragma unroll
    for (int mr = 0; mr < 2; ++mr) {
        const int r = wm * 32 + mr * 16 + fr;
        const float ss = red[0][r][0] + red[1][r][0];
        const float qq = red[0][r][1] + red[1][r][1];
        mean[mr] = ss * (1.f / 256.f);
        const float var = qq * (1.f / 256.f) - mean[mr] * mean[mr];
        rinv[mr] = rsqrtf(var + 1e-5f);
    }
    #pragma unroll
    for (int nr = 0; nr < 8; ++nr) {
        const int colbase = wn * 128 + nr * 16 + fq * 4;
        const float4 g4 = *(const float4*)&g[colbase];
        const float4 e4 = *(const float4*)&be[colbase];
        #pragma unroll
        for (int mr = 0; mr < 2; ++mr) {
            const int row = m0 + wm * 32 + mr * 16 + fr;
            const f4v x = acc[nr][mr];
            float y0 = (x[0] - mean[mr]) * rinv[mr] * g4.x + e4.x;
            float y1 = (x[1] - mean[mr]) * rinv[mr] * g4.y + e4.y;
            float y2 = (x[2] - mean[mr]) * rinv[mr] * g4.z + e4.z;
            float y3 = (x[3] - mean[mr]) * rinv[mr] * g4.w + e4.w;
            if (row < MstoreF)
                *(float4*)&outF[(size_t)row * 256 + colbase] = make_float4(y0, y1, y2, y3);
            if (STOREB) {
                union { ushort4 u; __hip_bfloat16 h[4]; } pk;
                pk.h[0] = __float2bfloat16(y0); pk.h[1] = __float2bfloat16(y1);
                pk.h[2] = __float2bfloat16(y2); pk.h[3] = __float2bfloat16(y3);
                *(ushort4*)&outB[(size_t)row * 256 + colbase] = pk.u;
            }
        }
    }
}

// =====================================================================
// all weight prep in one launch: transpose + bf16 convert
// =====================================================================
__global__ __launch_bounds__(256)
void prep_weights(const float* __restrict__ vW, const float* __restrict__ offW,
                  const float* __restrict__ awW, const float* __restrict__ outW,
                  const float* __restrict__ w1, const float* __restrict__ w2,
                  __hip_bfloat16* __restrict__ vWt, __hip_bfloat16* __restrict__ catWt,
                  __hip_bfloat16* __restrict__ outWt, __hip_bfloat16* __restrict__ w1t,
                  __hip_bfloat16* __restrict__ w2t)
{
    int i = blockIdx.x * 256 + threadIdx.x;   // 753664 total = 2944*256
    if (i < 65536) { const int n = i >> 8, k = i & 255;
        vWt[i] = __float2bfloat16(vW[(size_t)k * 256 + n]); return; }
    i -= 65536;
    if (i < 98304) { const int n = i >> 8, k = i & 255;
        catWt[i] = __float2bfloat16(n < 256 ? offW[(size_t)k * 256 + n]
                                            : awW[(size_t)k * 128 + n - 256]); return; }
    i -= 98304;
    if (i < 65536) { const int n = i >> 8, k = i & 255;
        outWt[i] = __float2bfloat16(outW[(size_t)k * 256 + n]); return; }
    i -= 65536;
    if (i < 262144) { const int n = i >> 8, k = i & 255;
        w1t[i] = __float2bfloat16(w1[(size_t)k * 1024 + n]); return; }
    i -= 262144;
    { const int n = i >> 10, k = i & 1023;
        w2t[i] = __float2bfloat16(w2[(size_t)k * 256 + n]); }
}

// ---------------- query / query+pos -> bf16 (padded rows -> 0), one pass ----
__global__ __launch_bounds__(256)
void cvt_both(const float* __restrict__ q, const float* __restrict__ qp,
              __hip_bfloat16* __restrict__ qb, __hip_bfloat16* __restrict__ qpb)
{
    const int i   = blockIdx.x * 256 + threadIdx.x;  // 8-elem chunk id
    const int row = i >> 5;
    union { u4v u; __hip_bfloat16 h[8]; } p1, p2;
    if (row >= NROW) {
        u4v z = {0u, 0u, 0u, 0u};
        p1.u = z; p2.u = z;
    } else {
        const size_t e = (size_t)i * 8;
        float4 x0 = *(const float4*)&q[e];
        float4 x1 = *(const float4*)&q[e + 4];
        float4 y0 = *(const float4*)&qp[e];
        float4 y1 = *(const float4*)&qp[e + 4];
        p1.h[0] = __float2bfloat16(x0.x); p1.h[1] = __float2bfloat16(x0.y);
        p1.h[2] = __float2bfloat16(x0.z); p1.h[3] = __float2bfloat16(x0.w);
        p1.h[4] = __float2bfloat16(x1.x); p1.h[5] = __float2bfloat16(x1.y);
        p1.h[6] = __float2bfloat16(x1.z); p1.h[7] = __float2bfloat16(x1.w);
        p2.h[0] = __float2bfloat16(x0.x + y0.x); p2.h[1] = __float2bfloat16(x0.y + y0.y);
        p2.h[2] = __float2bfloat16(x0.z + y0.z); p2.h[3] = __float2bfloat16(x0.w + y0.w);
        p2.h[4] = __float2bfloat16(x1.x + y1.x); p2.h[5] = __float2bfloat16(x1.y + y1.y);
        p2.h[6] = __float2bfloat16(x1.z + y1.z); p2.h[7] = __float2bfloat16(x1.w + y1.w);
    }
    *(u4v*)&qb[(size_t)i * 8]  = p1.u;
    *(u4v*)&qpb[(size_t)i * 8] = p2.u;
}

// =====================================================================
// MSDA sampling v3 (reads fused cat buffer, stride 384)
// =====================================================================
__device__ __forceinline__ float blo(unsigned u) { return __builtin_bit_cast(float, u << 16); }
__device__ __forceinline__ float bhi(unsigned u) { return __builtin_bit_cast(float, u & 0xffff0000u); }

__global__ __launch_bounds__(256)
void msda_sample3(const __hip_bfloat16* __restrict__ v, const float* __restrict__ cat,
                  const float* __restrict__ refp, __hip_bfloat16* __restrict__ accO)
{
    __shared__ int   sIdx[1024][4];
    __shared__ float sW[1024][4];
    const int row0 = blockIdx.x * 8;
    const int tid  = threadIdx.x;

    #pragma unroll
    for (int it = 0; it < 4; ++it) {
        const int item = it * 256 + tid;          // (r<<7)|(h<<4)|p
        const int p = item & 15, h = (item >> 4) & 7, r = item >> 7;
        const int row = row0 + r;
        const int lvl = p >> 2;
        const float logit = cat[(size_t)row * 384 + 256 + h * 16 + p];
        float mx = logit;
        #pragma unroll
        for (int o = 1; o < 16; o <<= 1) mx = fmaxf(mx, __shfl_xor(mx, o, 64));
        const float e = __expf(logit - mx);
        float s = e;
        #pragma unroll
        for (int o = 1; o < 16; o <<= 1) s += __shfl_xor(s, o, 64);
        const float aw = e / s;

        const int Hs[4] = {100, 50, 25, 13};
        const int Ss[4] = {0, 10000, 12500, 13125};
        const int   Wl = Hs[lvl];
        const float Wf = (float)Wl;
        const float ox = cat[(size_t)row * 384 + h * 32 + p * 2 + 0];
        const float oy = cat[(size_t)row * 384 + h * 32 + p * 2 + 1];
        const float rx = refp[(size_t)row * 8 + lvl * 2 + 0];
        const float ry = refp[(size_t)row * 8 + lvl * 2 + 1];
        const float x = (rx + ox / Wf) * Wf - 0.5f;
        const float y = (ry + oy / Wf) * Wf - 0.5f;
        const float x0f = floorf(x), y0f = floorf(y);
        const float lx = x - x0f, ly = y - y0f;
        const int x0 = (int)x0f, y0 = (int)y0f;
        const int b = row / Ll;
        const int vbase = b * Ll + Ss[lvl];
        int ixr[4]; float wr[4];
        #pragma unroll
        for (int c = 0; c < 4; ++c) {
            const int cy = c >> 1, cx = c & 1;
            const int yi = y0 + cy, xi = x0 + cx;
            const bool ok = (yi >= 0) & (yi < Wl) & (xi >= 0) & (xi < Wl);
            const int yc = min(max(yi, 0), Wl - 1);
            const int xc = min(max(xi, 0), Wl - 1);
            const float wt = (cy ? ly : 1.f - ly) * (cx ? lx : 1.f - lx);
            ixr[c] = (vbase + yc * Wl + xc) * 512;
            wr[c]  = ok ? aw * wt : 0.f;
        }
        const int item2 = (item & ~15) | ((item & 15) ^ h);  // bank swizzle
        *(int4*)&sIdx[item2][0] = make_int4(ixr[0], ixr[1], ixr[2], ixr[3]);
        *(float4*)&sW[item2][0] = make_float4(wr[0], wr[1], wr[2], wr[3]);
    }
    __syncthreads();

    const int r   = tid >> 5;
    const int h   = (tid >> 2) & 7;
    const int oct = tid & 3;
    const int row = row0 + r;
    const char* vB = (const char*)v + (h * 32 + oct * 8) * 2;
    const int ibase = r * 128 + h * 16;
    float acc[8] = {};
    #pragma unroll
    for (int i = 0; i < 16; ++i) {
        const int idx = ibase + (i ^ h);
        const int4   ix = *(const int4*)&sIdx[idx][0];
        const float4 wv = *(const float4*)&sW[idx][0];
        u4v u0 = *(const u4v*)(vB + (unsigned)ix.x);
        u4v u1 = *(const u4v*)(vB + (unsigned)ix.y);
        u4v u2 = *(const u4v*)(vB + (unsigned)ix.z);
        u4v u3 = *(const u4v*)(vB + (unsigned)ix.w);
        #pragma unroll
        for (int q = 0; q < 4; ++q) {
            acc[2*q]   = fmaf(wv.x, blo(u0[q]), acc[2*q]);
            acc[2*q+1] = fmaf(wv.x, bhi(u0[q]), acc[2*q+1]);
            acc[2*q]   = fmaf(wv.y, blo(u1[q]), acc[2*q]);
            acc[2*q+1] = fmaf(wv.y, bhi(u1[q]), acc[2*q+1]);
            acc[2*q]   = fmaf(wv.z, blo(u2[q]), acc[2*q]);
            acc[2*q+1] = fmaf(wv.z, bhi(u2[q]), acc[2*q+1]);
            acc[2*q]   = fmaf(wv.w, blo(u3[q]), acc[2*q]);
            acc[2*q+1] = fmaf(wv.w, bhi(u3[q]), acc[2*q+1]);
        }
    }
    union { u4v u; __hip_bfloat16 hh[8]; } pk;
    #pragma unroll
    for (int q = 0; q < 8; ++q) pk.hh[q] = __float2bfloat16(acc[q]);
    *(u4v*)&accO[(size_t)row * 256 + h * 32 + oct * 8] = pk.u;
}

// =====================================================================
// launcher
// =====================================================================
extern "C" void kernel_launch(void* const* d_in, const int* in_sizes, int n_in,
                              void* d_out, int out_size, void* d_ws, size_t ws_size,
                              hipStream_t stream)
{
    (void)in_sizes; (void)n_in; (void)out_size; (void)ws_size;
    const float* query = (const float*)d_in[0];
    const float* qpos  = (const float*)d_in[1];
    const float* refp  = (const float*)d_in[2];
    const float* v_W   = (const float*)d_in[5];
    const float* v_b   = (const float*)d_in[6];
    const float* off_W = (const float*)d_in[7];
    const float* off_b = (const float*)d_in[8];
    const float* aw_W  = (const float*)d_in[9];
    const float* aw_b  = (const float*)d_in[10];
    const float* out_W = (const float*)d_in[11];
    const float* out_b = (const float*)d_in[12];
    const float* ln1g  = (const float*)d_in[13];
    const float* ln1b  = (const float*)d_in[14];
    const float* w1    = (const float*)d_in[15];
    const float* b1    = (const float*)d_in[16];
    const float* w2    = (const float*)d_in[17];
    const float* b2    = (const float*)d_in[18];
    const float* ln2g  = (const float*)d_in[19];
    const float* ln2b  = (const float*)d_in[20];
    float* out = (float*)d_out;

    char* ws = (char*)d_ws;
    // arena (peak 165.2 MB):
    //   [0, 81.8M)        catf f32 [MP][384]   } -> hbuf bf16 [MP][1024] spans [0,109.1M)
    //   [81.8M, 109.1M)   qb bf16 -> accb      }    (catf+qb dead by ffn1)
    //   [109.1M, 136.4M)  qpb bf16             (dead after cat-gemm)
    //   [136.4M, 163.7M)  vbuf bf16 -> xb bf16 (vbuf dead after msda)
    //   [163.7M, 165.2M)  weights
    constexpr size_t CATF_B = (size_t)MP * 384 * 4;     //  81,788,928
    constexpr size_t HALF_B = (size_t)MP * 256 * 2;     //  27,262,976
    float*          catf = (float*)ws;
    __hip_bfloat16* qb   = (__hip_bfloat16*)(ws + CATF_B);
    __hip_bfloat16* qpb  = (__hip_bfloat16*)(ws + CATF_B + HALF_B);
    __hip_bfloat16* vbuf = (__hip_bfloat16*)(ws + CATF_B + 2 * HALF_B);
    __hip_bfloat16* accb = qb;
    __hip_bfloat16* xb   = vbuf;
    __hip_bfloat16* hbuf = (__hip_bfloat16*)ws;
    char* wsw = ws + CATF_B + 3 * HALF_B;
    __hip_bfloat16* vWt   = (__hip_bfloat16*)(wsw);
    __hip_bfloat16* catWt = (__hip_bfloat16*)(wsw + 131072);
    __hip_bfloat16* outWt = (__hip_bfloat16*)(wsw + 327680);
    __hip_bfloat16* w1t   = (__hip_bfloat16*)(wsw + 458752);
    __hip_bfloat16* w2t   = (__hip_bfloat16*)(wsw + 983040);

    dim3 blk(256);

    prep_weights<<<2944, blk, 0, stream>>>(v_W, off_W, aw_W, out_W, w1, w2,
                                           vWt, catWt, outWt, w1t, w2t);
    cvt_both<<<MP / 8, blk, 0, stream>>>(query, qpos, qb, qpb);

    // v = query @ v_W + v_b  (bf16 out)
    gemm_mfma<false, false, true><<<dim3(2, MP / 128), blk, 0, stream>>>(
        qb, vWt, v_b, nullptr, nullptr, vbuf, MP, 256, 256);
    // cat = (q+pos) @ [off_W | aw_W] + [off_b | aw_b]  (f32 out, N=384)
    gemm_mfma<false, true, false><<<dim3(3, MP / 128), blk, 0, stream>>>(
        qpb, catWt, off_b, aw_b, catf, nullptr, MP, 384, 256);

    // deformable sampling
    msda_sample3<<<NROW / 8, blk, 0, stream>>>(vbuf, catf, refp, accb);

    // x = LN1(query + acc @ out_W + out_b) -> xb (bf16 only)
    gemm_ln<true, false><<<MP / 64, blk, 0, stream>>>(
        accb, outWt, out_b, query, nullptr, NROW, ln1g, ln1b,
        nullptr, 0, xb, 256);

    // h = relu(x @ w1 + b1) -> hbuf  (single launch, un-chunked)
    gemm_mfma<true, false, true><<<dim3(8, MP / 128), blk, 0, stream>>>(
        xb, w1t, b1, nullptr, nullptr, hbuf, MP, 1024, 256);

    // out = LN2(x + h @ w2 + b2)  (single launch)
    gemm_ln<false, true><<<MP / 64, blk, 0, stream>>>(
        hbuf, w2t, b2, nullptr, xb, MP, ln2g, ln2b,
        out, NROW, nullptr, 1024);
}